// Round 2
// baseline (1166.565 us; speedup 1.0000x reference)
//
#include <hip/hip_runtime.h>
#include <hip/hip_bf16.h>
#include <stdint.h>

// GQA fused pipeline for MI355X (gfx950).
// B=2, N=S=2048, D_IN=D_OUT=2048, H=16, KV=4, d=128, GROUP=4.
// Head permutation: output head p <-> q-head hq=(p%4)*4+p/4, kv head = p%4.
// Precision: bf16x3 split (hi/lo) for Q/K projections and QK^T (softmax is
// exp-sensitive, scores ~N(0,11) unscaled); plain bf16 for V/PV/O-proj.
// Softmax WITHOUT max subtraction: max score ~69 -> exp fits fp32/bf16 range.
// Pass A accumulates row-sum l only; pass B recomputes S, writes w=exp(S)/l.

typedef __attribute__((ext_vector_type(4))) float f32x4;
typedef __attribute__((ext_vector_type(8))) short short8;

#define GLDS(gsrc, ldst) __builtin_amdgcn_global_load_lds( \
  (const __attribute__((address_space(1))) void*)(gsrc),   \
  (__attribute__((address_space(3))) void*)(ldst), 16, 0, 0)

__device__ __forceinline__ f32x4 MFMA(short8 a, short8 b, f32x4 c) {
  return __builtin_amdgcn_mfma_f32_16x16x32_bf16(a, b, c, 0, 0, 0);
}

__device__ __forceinline__ unsigned short f2bf(float f) {
  union { float f; uint32_t u; } v; v.f = f;
  uint32_t r = v.u + 0x7FFFu + ((v.u >> 16) & 1u);
  return (unsigned short)(r >> 16);
}
__device__ __forceinline__ float bf2f(unsigned short h) {
  union { uint32_t u; float f; } v; v.u = ((uint32_t)h) << 16;
  return v.f;
}
// XOR swizzles (both-sides-or-neither, guide rule 21): rows of 128B / 256B.
__device__ __forceinline__ int swz128(int r, int byte) {
  return r * 128 + (byte ^ ((r & 7) << 4));
}
__device__ __forceinline__ int swz256(int r, int byte) {
  return r * 256 + ((byte & 15) | ((((byte >> 4) & 15) ^ (r & 15)) << 4));
}

// ---------------- weight transpose + hi/lo split ----------------
// W[K][C] fp32 -> Thi[C][K] bf16 (+ Tlo residual if non-null)
__global__ __launch_bounds__(1024) void transpose_split(
    const float* __restrict__ W, unsigned short* __restrict__ Thi,
    unsigned short* __restrict__ Tlo, int K, int C) {
  __shared__ float tile[32][33];
  int c0 = blockIdx.x * 32, k0 = blockIdx.y * 32;
  int tx = threadIdx.x, ty = threadIdx.y;
  tile[ty][tx] = W[(size_t)(k0 + ty) * C + c0 + tx];
  __syncthreads();
  float f = tile[tx][ty];
  size_t o = (size_t)(c0 + ty) * K + k0 + tx;
  unsigned short hi = f2bf(f);
  Thi[o] = hi;
  if (Tlo) Tlo[o] = f2bf(f - bf2f(hi));
}

// ---------------- projection GEMM ----------------
// Y = X(fp32 [4096][2048]) @ W  with W given as WT[C][2048] bf16 hi(/lo).
// MODE 0: split (bf16x3), outputs hi/lo row-major [4096][Ctot].
// MODE 1: plain bf16, output to VT layout [b][c][n] (pre-transposed V).
template <int MODE>
__global__ __launch_bounds__(256, 2) void proj_kernel(
    const float* __restrict__ X,
    const unsigned short* __restrict__ WTh,
    const unsigned short* __restrict__ WTl,
    unsigned short* __restrict__ Oh,
    unsigned short* __restrict__ Ol,
    int Ctot) {
  __shared__ __align__(16) unsigned short xh[128 * 64];
  __shared__ __align__(16) unsigned short xl[128 * 64];
  __shared__ __align__(16) unsigned short wh[128 * 64];
  __shared__ __align__(16) unsigned short wl[128 * 64];
  const int t = threadIdx.x;
  const int n0 = blockIdx.x * 128, m0 = blockIdx.y * 128;
  const int wid = t >> 6, lane = t & 63;
  const int wm = (wid >> 1) * 64, wn = (wid & 1) * 64;
  f32x4 acc[4][4] = {};
  for (int k0 = 0; k0 < 2048; k0 += 64) {
    // stage X tile 128x64 fp32 -> bf16 hi/lo (swizzled ds_write)
    #pragma unroll
    for (int i = 0; i < 8; ++i) {
      int e = (i * 256 + t) * 4;
      int r = e >> 6, c = e & 63;
      float4 f = *(const float4*)(X + (size_t)(m0 + r) * 2048 + k0 + c);
      unsigned short h0 = f2bf(f.x), h1 = f2bf(f.y), h2 = f2bf(f.z), h3 = f2bf(f.w);
      int off = swz128(r, c * 2);
      *(uint2*)((char*)xh + off) = make_uint2((unsigned)h0 | ((unsigned)h1 << 16),
                                              (unsigned)h2 | ((unsigned)h3 << 16));
      if (MODE == 0) {
        unsigned short l0 = f2bf(f.x - bf2f(h0)), l1 = f2bf(f.y - bf2f(h1));
        unsigned short l2 = f2bf(f.z - bf2f(h2)), l3 = f2bf(f.w - bf2f(h3));
        *(uint2*)((char*)xl + off) = make_uint2((unsigned)l0 | ((unsigned)l1 << 16),
                                                (unsigned)l2 | ((unsigned)l3 << 16));
      }
    }
    // stage W tile 128x64 bf16 via global_load_lds, pre-swizzled source
    #pragma unroll
    for (int i = 0; i < 4; ++i) {
      int L = i * 4096 + t * 16;
      int r = L >> 7;
      int ss = ((L >> 4) & 7) ^ (r & 7);
      GLDS(WTh + (size_t)(n0 + r) * 2048 + k0 + ss * 8, (char*)wh + i * 4096 + wid * 1024);
      if (MODE == 0)
        GLDS(WTl + (size_t)(n0 + r) * 2048 + k0 + ss * 8, (char*)wl + i * 4096 + wid * 1024);
    }
    __syncthreads();
    #pragma unroll
    for (int ks = 0; ks < 2; ++ks) {
      const int kb = ks * 64 + (lane >> 4) * 16;
      short8 ah[4], al[4], bh[4], bl[4];
      #pragma unroll
      for (int mi = 0; mi < 4; ++mi) {
        int r = wm + mi * 16 + (lane & 15);
        ah[mi] = *(const short8*)((char*)xh + swz128(r, kb));
        if (MODE == 0) al[mi] = *(const short8*)((char*)xl + swz128(r, kb));
      }
      #pragma unroll
      for (int ni = 0; ni < 4; ++ni) {
        int r = wn + ni * 16 + (lane & 15);
        bh[ni] = *(const short8*)((char*)wh + swz128(r, kb));
        if (MODE == 0) bl[ni] = *(const short8*)((char*)wl + swz128(r, kb));
      }
      #pragma unroll
      for (int mi = 0; mi < 4; ++mi)
        #pragma unroll
        for (int ni = 0; ni < 4; ++ni) {
          acc[mi][ni] = MFMA(ah[mi], bh[ni], acc[mi][ni]);
          if (MODE == 0) {
            acc[mi][ni] = MFMA(al[mi], bh[ni], acc[mi][ni]);
            acc[mi][ni] = MFMA(ah[mi], bl[ni], acc[mi][ni]);
          }
        }
    }
    __syncthreads();
  }
  #pragma unroll
  for (int mi = 0; mi < 4; ++mi)
    #pragma unroll
    for (int ni = 0; ni < 4; ++ni)
      #pragma unroll
      for (int rg = 0; rg < 4; ++rg) {
        int row = m0 + wm + mi * 16 + (lane >> 4) * 4 + rg;
        int col = n0 + wn + ni * 16 + (lane & 15);
        float y = acc[mi][ni][rg];
        if (MODE == 0) {
          unsigned short hi = f2bf(y);
          size_t o = (size_t)row * Ctot + col;
          Oh[o] = hi;
          Ol[o] = f2bf(y - bf2f(hi));
        } else {
          // VT[b][c][n] : b = row>>11, n = row&2047
          Oh[((size_t)(row >> 11) * 512 + col) * 2048 + (row & 2047)] = f2bf(y);
        }
      }
}

// ---------------- fused attention ----------------
// One block: 128 q-rows of one (b,p). 4 waves x 32 rows. Q kept in regs
// (hi/lo). Pass A: row-sum l of exp(S) (no max needed, fp32 range safe).
// Pass B: recompute S, write w=exp(S)/l (fp32, the big output), P->LDS,
// PV MFMA (plain bf16).
__global__ __launch_bounds__(256, 2) void attn_kernel(
    const unsigned short* __restrict__ Qh, const unsigned short* __restrict__ Ql,
    const unsigned short* __restrict__ Kh, const unsigned short* __restrict__ Kl,
    const unsigned short* __restrict__ VT,
    float* __restrict__ Wout,
    unsigned short* __restrict__ Ctx) {
  __shared__ __align__(16) char lds[65536];
  const int bp = blockIdx.y;
  const int b = bp >> 4, p = bp & 15;
  const int hq = (p & 3) * 4 + (p >> 2);
  const int kv = p & 3;
  const int n0 = blockIdx.x * 128;
  const int t = threadIdx.x, wid = t >> 6, lane = t & 63;
  const int wrow = wid * 32;

  // stage Q tile (128 x 128d) hi/lo, then load A-frags to regs
  {
    size_t qbase = ((size_t)(b * 2048 + n0)) * 2048 + hq * 128;
    #pragma unroll
    for (int i = 0; i < 8; ++i) {
      int L = i * 4096 + t * 16;
      int r = L >> 8;
      int ss = ((L >> 4) & 15) ^ (r & 15);
      GLDS(Qh + qbase + (size_t)r * 2048 + ss * 8, lds + i * 4096 + wid * 1024);
      GLDS(Ql + qbase + (size_t)r * 2048 + ss * 8, lds + 32768 + i * 4096 + wid * 1024);
    }
  }
  __syncthreads();
  short8 qa_h[2][4], qa_l[2][4];
  #pragma unroll
  for (int mf = 0; mf < 2; ++mf)
    #pragma unroll
    for (int ks = 0; ks < 4; ++ks) {
      int r = wrow + mf * 16 + (lane & 15);
      int byte = ks * 64 + (lane >> 4) * 16;
      qa_h[mf][ks] = *(const short8*)(lds + swz256(r, byte));
      qa_l[mf][ks] = *(const short8*)(lds + 32768 + swz256(r, byte));
    }
  __syncthreads();

  const size_t kbase = (size_t)b * 2048 * 512 + kv * 128;
  float lp[2][4];
  #pragma unroll
  for (int mf = 0; mf < 2; ++mf)
    #pragma unroll
    for (int rg = 0; rg < 4; ++rg) lp[mf][rg] = 0.f;

  // ---- pass A: row-sum of exp(S) ----
  for (int s0 = 0; s0 < 2048; s0 += 64) {
    #pragma unroll
    for (int i = 0; i < 4; ++i) {
      int L = i * 4096 + t * 16;
      int r = L >> 8;
      int ss = ((L >> 4) & 15) ^ (r & 15);
      GLDS(Kh + kbase + (size_t)(s0 + r) * 512 + ss * 8, lds + i * 4096 + wid * 1024);
      GLDS(Kl + kbase + (size_t)(s0 + r) * 512 + ss * 8, lds + 16384 + i * 4096 + wid * 1024);
    }
    __syncthreads();
    f32x4 sc[2][4] = {};
    #pragma unroll
    for (int sf = 0; sf < 4; ++sf)
      #pragma unroll
      for (int ks = 0; ks < 4; ++ks) {
        int r = sf * 16 + (lane & 15);
        int byte = ks * 64 + (lane >> 4) * 16;
        short8 bh = *(const short8*)(lds + swz256(r, byte));
        short8 bl = *(const short8*)(lds + 16384 + swz256(r, byte));
        #pragma unroll
        for (int mf = 0; mf < 2; ++mf) {
          sc[mf][sf] = MFMA(qa_h[mf][ks], bh, sc[mf][sf]);
          sc[mf][sf] = MFMA(qa_l[mf][ks], bh, sc[mf][sf]);
          sc[mf][sf] = MFMA(qa_h[mf][ks], bl, sc[mf][sf]);
        }
      }
    #pragma unroll
    for (int mf = 0; mf < 2; ++mf)
      #pragma unroll
      for (int rg = 0; rg < 4; ++rg)
        lp[mf][rg] += __expf(sc[mf][0][rg]) + __expf(sc[mf][1][rg]) +
                      __expf(sc[mf][2][rg]) + __expf(sc[mf][3][rg]);
    __syncthreads();
  }

  // reduce l over the 16 lanes holding each row's s-columns
  float invl[2][4];
  #pragma unroll
  for (int mf = 0; mf < 2; ++mf)
    #pragma unroll
    for (int rg = 0; rg < 4; ++rg) {
      float sm = lp[mf][rg];
      sm += __shfl_xor(sm, 1);
      sm += __shfl_xor(sm, 2);
      sm += __shfl_xor(sm, 4);
      sm += __shfl_xor(sm, 8);
      invl[mf][rg] = 1.0f / sm;
    }

  // ---- pass B: recompute S, write weights, PV ----
  f32x4 cacc[2][8] = {};
  const size_t vbase = ((size_t)b * 512 + kv * 128) * 2048;
  const size_t wbase = ((size_t)bp * 2048 + n0) * 2048;
  for (int s0 = 0; s0 < 2048; s0 += 64) {
    #pragma unroll
    for (int i = 0; i < 4; ++i) {
      int L = i * 4096 + t * 16;
      int r = L >> 8;
      int ss = ((L >> 4) & 15) ^ (r & 15);
      GLDS(Kh + kbase + (size_t)(s0 + r) * 512 + ss * 8, lds + i * 4096 + wid * 1024);
      GLDS(Kl + kbase + (size_t)(s0 + r) * 512 + ss * 8, lds + 16384 + i * 4096 + wid * 1024);
    }
    #pragma unroll
    for (int i = 0; i < 4; ++i) {
      int L = i * 4096 + t * 16;
      int r = L >> 7;
      int ss = ((L >> 4) & 7) ^ (r & 7);
      GLDS(VT + vbase + (size_t)r * 2048 + s0 + ss * 8, lds + 32768 + i * 4096 + wid * 1024);
    }
    __syncthreads();
    f32x4 sc[2][4] = {};
    #pragma unroll
    for (int sf = 0; sf < 4; ++sf)
      #pragma unroll
      for (int ks = 0; ks < 4; ++ks) {
        int r = sf * 16 + (lane & 15);
        int byte = ks * 64 + (lane >> 4) * 16;
        short8 bh = *(const short8*)(lds + swz256(r, byte));
        short8 bl = *(const short8*)(lds + 16384 + swz256(r, byte));
        #pragma unroll
        for (int mf = 0; mf < 2; ++mf) {
          sc[mf][sf] = MFMA(qa_h[mf][ks], bh, sc[mf][sf]);
          sc[mf][sf] = MFMA(qa_l[mf][ks], bh, sc[mf][sf]);
          sc[mf][sf] = MFMA(qa_h[mf][ks], bl, sc[mf][sf]);
        }
      }
    // normalized weights -> global (fp32) + P -> LDS (bf16, per-wave region)
    #pragma unroll
    for (int mf = 0; mf < 2; ++mf)
      #pragma unroll
      for (int sf = 0; sf < 4; ++sf)
        #pragma unroll
        for (int rg = 0; rg < 4; ++rg) {
          float w = __expf(sc[mf][sf][rg]) * invl[mf][rg];
          int lr = mf * 16 + (lane >> 4) * 4 + rg;
          int col = sf * 16 + (lane & 15);
          Wout[wbase + (size_t)(wrow + lr) * 2048 + s0 + col] = w;
          *(unsigned short*)(lds + 49152 + wid * 4096 + swz128(lr, col * 2)) = f2bf(w);
        }
    // PV: ctx[32 x 128] += P[32 x 64] @ V[64 x 128]
    #pragma unroll
    for (int ks = 0; ks < 2; ++ks) {
      short8 pa[2];
      #pragma unroll
      for (int mf = 0; mf < 2; ++mf)
        pa[mf] = *(const short8*)(lds + 49152 + wid * 4096 +
                                  swz128(mf * 16 + (lane & 15), ks * 64 + (lane >> 4) * 16));
      #pragma unroll
      for (int df = 0; df < 8; ++df) {
        short8 vb = *(const short8*)(lds + 32768 +
                                     swz128(df * 16 + (lane & 15), ks * 64 + (lane >> 4) * 16));
        #pragma unroll
        for (int mf = 0; mf < 2; ++mf)
          cacc[mf][df] = MFMA(pa[mf], vb, cacc[mf][df]);
      }
    }
    __syncthreads();
  }
  // ctx epilogue -> bf16 [4096][2048], channel = p*128+d
  #pragma unroll
  for (int mf = 0; mf < 2; ++mf)
    #pragma unroll
    for (int df = 0; df < 8; ++df)
      #pragma unroll
      for (int rg = 0; rg < 4; ++rg) {
        int grow = b * 2048 + n0 + wrow + mf * 16 + (lane >> 4) * 4 + rg;
        int col = p * 128 + df * 16 + (lane & 15);
        Ctx[(size_t)grow * 2048 + col] = f2bf(cacc[mf][df][rg]);
      }
}

// ---------------- output projection (plain bf16) ----------------
__global__ __launch_bounds__(256, 2) void gemm_out(
    const unsigned short* __restrict__ A,   // ctx bf16 [4096][2048]
    const unsigned short* __restrict__ BT,  // WoT bf16 [2048][2048]
    float* __restrict__ Cout) {             // [4096][2048]
  __shared__ __align__(16) unsigned short ash[128 * 64];
  __shared__ __align__(16) unsigned short bsh[128 * 64];
  const int t = threadIdx.x;
  const int n0 = blockIdx.x * 128, m0 = blockIdx.y * 128;
  const int wid = t >> 6, lane = t & 63;
  const int wm = (wid >> 1) * 64, wn = (wid & 1) * 64;
  f32x4 acc[4][4] = {};
  for (int k0 = 0; k0 < 2048; k0 += 64) {
    #pragma unroll
    for (int i = 0; i < 4; ++i) {
      int L = i * 4096 + t * 16;
      int r = L >> 7;
      int ss = ((L >> 4) & 7) ^ (r & 7);
      GLDS(A + (size_t)(m0 + r) * 2048 + k0 + ss * 8, (char*)ash + i * 4096 + wid * 1024);
      GLDS(BT + (size_t)(n0 + r) * 2048 + k0 + ss * 8, (char*)bsh + i * 4096 + wid * 1024);
    }
    __syncthreads();
    #pragma unroll
    for (int ks = 0; ks < 2; ++ks) {
      const int kb = ks * 64 + (lane >> 4) * 16;
      short8 af[4], bfr[4];
      #pragma unroll
      for (int mi = 0; mi < 4; ++mi)
        af[mi] = *(const short8*)((char*)ash + swz128(wm + mi * 16 + (lane & 15), kb));
      #pragma unroll
      for (int ni = 0; ni < 4; ++ni)
        bfr[ni] = *(const short8*)((char*)bsh + swz128(wn + ni * 16 + (lane & 15), kb));
      #pragma unroll
      for (int mi = 0; mi < 4; ++mi)
        #pragma unroll
        for (int ni = 0; ni < 4; ++ni)
          acc[mi][ni] = MFMA(af[mi], bfr[ni], acc[mi][ni]);
    }
    __syncthreads();
  }
  #pragma unroll
  for (int mi = 0; mi < 4; ++mi)
    #pragma unroll
    for (int ni = 0; ni < 4; ++ni)
      #pragma unroll
      for (int rg = 0; rg < 4; ++rg) {
        int row = m0 + wm + mi * 16 + (lane >> 4) * 4 + rg;
        int col = n0 + wn + ni * 16 + (lane & 15);
        Cout[(size_t)row * 2048 + col] = acc[mi][ni][rg];
      }
}

extern "C" void kernel_launch(void* const* d_in, const int* in_sizes, int n_in,
                              void* d_out, int out_size, void* d_ws, size_t ws_size,
                              hipStream_t stream) {
  const float* query = (const float*)d_in[0];
  const float* key   = (const float*)d_in[1];
  const float* value = (const float*)d_in[2];
  const float* Wq = (const float*)d_in[3];
  const float* Wk = (const float*)d_in[4];
  const float* Wv = (const float*)d_in[5];
  const float* Wo = (const float*)d_in[6];
  float* out = (float*)d_out;            // attn_output: 2*2048*2048 fp32
  float* wts = out + 8388608;            // weights: 32*2048*2048 fp32

  char* ws = (char*)d_ws;
  unsigned short* wqT_h = (unsigned short*)(ws);             // 8388608 B
  unsigned short* wqT_l = (unsigned short*)(ws + 8388608);   // 8388608
  unsigned short* wkT_h = (unsigned short*)(ws + 16777216);  // 2097152
  unsigned short* wkT_l = (unsigned short*)(ws + 18874368);  // 2097152
  unsigned short* wvT_h = (unsigned short*)(ws + 20971520);  // 2097152
  unsigned short* q_h   = (unsigned short*)(ws + 23068672);  // 16777216
  unsigned short* q_l   = (unsigned short*)(ws + 39845888);  // 16777216
  unsigned short* k_h   = (unsigned short*)(ws + 56623104);  // 4194304
  unsigned short* k_l   = (unsigned short*)(ws + 60817408);  // 4194304
  unsigned short* vT    = (unsigned short*)(ws + 65011712);  // 4194304  (tot 66 MB)
  unsigned short* ctxb  = (unsigned short*)(ws);             // alias wqT_h/l (dead by attn), 16 MB
  unsigned short* woT   = (unsigned short*)(ws + 23068672);  // alias q_h (dead by O-proj), 8 MB

  transpose_split<<<dim3(64, 64), dim3(32, 32), 0, stream>>>(Wq, wqT_h, wqT_l, 2048, 2048);
  transpose_split<<<dim3(16, 64), dim3(32, 32), 0, stream>>>(Wk, wkT_h, wkT_l, 2048, 512);
  transpose_split<<<dim3(16, 64), dim3(32, 32), 0, stream>>>(Wv, wvT_h, (unsigned short*)nullptr, 2048, 512);
  proj_kernel<0><<<dim3(16, 32), dim3(256), 0, stream>>>(query, wqT_h, wqT_l, q_h, q_l, 2048);
  proj_kernel<0><<<dim3(4, 32), dim3(256), 0, stream>>>(key, wkT_h, wkT_l, k_h, k_l, 512);
  proj_kernel<1><<<dim3(4, 32), dim3(256), 0, stream>>>(value, wvT_h, (const unsigned short*)nullptr,
                                                        vT, (unsigned short*)nullptr, 512);
  attn_kernel<<<dim3(16, 32), dim3(256), 0, stream>>>(q_h, q_l, k_h, k_l, vT, wts, ctxb);
  transpose_split<<<dim3(64, 64), dim3(32, 32), 0, stream>>>(Wo, woT, (unsigned short*)nullptr, 2048, 2048);
  gemm_out<<<dim3(16, 32), dim3(256), 0, stream>>>(ctxb, woT, out);
}

// Round 3
// 1074.280 us; speedup vs baseline: 1.0859x; 1.0859x over previous
//
#include <hip/hip_runtime.h>
#include <hip/hip_bf16.h>
#include <stdint.h>

// GQA fused pipeline for MI355X (gfx950).
// B=2, N=S=2048, D_IN=D_OUT=2048, H=16, KV=4, d=128, GROUP=4.
// Head perm: output head p <-> q-head hq=(p&3)*4+(p>>2), kv head = p&3.
// Precision: bf16x3 split (hi/lo) for Q/K projections and QK^T; plain bf16
// for V/PV/O-proj. Softmax WITHOUT max subtraction (scores ~N(0,11), max ~69,
// exp fits fp32). Pass A: row-sum l only. Pass B: recompute S, w=exp(S)/l.
// R3 change: inputs pre-converted to bf16 hi/lo ONCE (was: per-tile in-loop
// VALU conversion, redone 16x per X tile); K-proj+V-proj merged into one
// 256-block launch (was 2x 128-block half-idle launches).

typedef __attribute__((ext_vector_type(4))) float f32x4;
typedef __attribute__((ext_vector_type(8))) short short8;

#define GLDS(gsrc, ldst) __builtin_amdgcn_global_load_lds( \
  (const __attribute__((address_space(1))) void*)(gsrc),   \
  (__attribute__((address_space(3))) void*)(ldst), 16, 0, 0)

__device__ __forceinline__ f32x4 MFMA(short8 a, short8 b, f32x4 c) {
  return __builtin_amdgcn_mfma_f32_16x16x32_bf16(a, b, c, 0, 0, 0);
}

__device__ __forceinline__ unsigned short f2bf(float f) {
  union { float f; uint32_t u; } v; v.f = f;
  uint32_t r = v.u + 0x7FFFu + ((v.u >> 16) & 1u);
  return (unsigned short)(r >> 16);
}
__device__ __forceinline__ float bf2f(unsigned short h) {
  union { uint32_t u; float f; } v; v.u = ((uint32_t)h) << 16;
  return v.f;
}
// XOR swizzles (both-sides-or-neither, guide rule 21): rows of 128B / 256B.
__device__ __forceinline__ int swz128(int r, int byte) {
  return r * 128 + (byte ^ ((r & 7) << 4));
}
__device__ __forceinline__ int swz256(int r, int byte) {
  return r * 256 + ((byte & 15) | ((((byte >> 4) & 15) ^ (r & 15)) << 4));
}

// ---------------- input conversion: fp32 -> bf16 hi/lo ----------------
// 3 segments of 8192 blocks: query (hi+lo), key (hi+lo), value (hi only).
__global__ __launch_bounds__(256) void convert_split3(
    const float* __restrict__ q, const float* __restrict__ k,
    const float* __restrict__ v,
    unsigned short* __restrict__ qh, unsigned short* __restrict__ ql,
    unsigned short* __restrict__ kh, unsigned short* __restrict__ kl,
    unsigned short* __restrict__ vh) {
  const int seg = blockIdx.x >> 13;
  const int idx = ((blockIdx.x & 8191) * 256 + threadIdx.x) * 4;
  const float* src = seg == 0 ? q : seg == 1 ? k : v;
  float4 f = *(const float4*)(src + idx);
  unsigned short h0 = f2bf(f.x), h1 = f2bf(f.y), h2 = f2bf(f.z), h3 = f2bf(f.w);
  unsigned short* Hd = seg == 0 ? qh : seg == 1 ? kh : vh;
  *(uint2*)(Hd + idx) = make_uint2((unsigned)h0 | ((unsigned)h1 << 16),
                                   (unsigned)h2 | ((unsigned)h3 << 16));
  if (seg < 2) {
    unsigned short l0 = f2bf(f.x - bf2f(h0)), l1 = f2bf(f.y - bf2f(h1));
    unsigned short l2 = f2bf(f.z - bf2f(h2)), l3 = f2bf(f.w - bf2f(h3));
    unsigned short* Ld = seg == 0 ? ql : kl;
    *(uint2*)(Ld + idx) = make_uint2((unsigned)l0 | ((unsigned)l1 << 16),
                                     (unsigned)l2 | ((unsigned)l3 << 16));
  }
}

// ---------------- weight transpose + hi/lo split ----------------
// W[K][C] fp32 -> Thi[C][K] bf16 (+ Tlo residual if non-null)
__global__ __launch_bounds__(1024) void transpose_split(
    const float* __restrict__ W, unsigned short* __restrict__ Thi,
    unsigned short* __restrict__ Tlo, int K, int C) {
  __shared__ float tile[32][33];
  int c0 = blockIdx.x * 32, k0 = blockIdx.y * 32;
  int tx = threadIdx.x, ty = threadIdx.y;
  tile[ty][tx] = W[(size_t)(k0 + ty) * C + c0 + tx];
  __syncthreads();
  float f = tile[tx][ty];
  size_t o = (size_t)(c0 + ty) * K + k0 + tx;
  unsigned short hi = f2bf(f);
  Thi[o] = hi;
  if (Tlo) Tlo[o] = f2bf(f - bf2f(hi));
}

// ---------------- Q projection GEMM (bf16x3) ----------------
// Y = A @ W, A given as Ah/Al bf16 [4096][2048], W as WT[C][2048] hi/lo.
// Outputs hi/lo row-major [4096][2048]. Pure GLDS staging, no in-loop VALU.
__global__ __launch_bounds__(256, 2) void qproj_kernel(
    const unsigned short* __restrict__ Ah, const unsigned short* __restrict__ Al,
    const unsigned short* __restrict__ WTh, const unsigned short* __restrict__ WTl,
    unsigned short* __restrict__ Oh, unsigned short* __restrict__ Ol) {
  __shared__ __align__(16) unsigned short xh[128 * 64];
  __shared__ __align__(16) unsigned short xl[128 * 64];
  __shared__ __align__(16) unsigned short wh[128 * 64];
  __shared__ __align__(16) unsigned short wl[128 * 64];
  const int t = threadIdx.x;
  const int n0 = blockIdx.x * 128, m0 = blockIdx.y * 128;
  const int wid = t >> 6, lane = t & 63;
  const int wm = (wid >> 1) * 64, wn = (wid & 1) * 64;
  f32x4 acc[4][4] = {};
  for (int k0 = 0; k0 < 2048; k0 += 64) {
    #pragma unroll
    for (int i = 0; i < 4; ++i) {
      int L = i * 4096 + t * 16;
      int r = L >> 7;
      int ss = ((L >> 4) & 7) ^ (r & 7);
      int dst = i * 4096 + wid * 1024;
      GLDS(Ah  + (size_t)(m0 + r) * 2048 + k0 + ss * 8, (char*)xh + dst);
      GLDS(Al  + (size_t)(m0 + r) * 2048 + k0 + ss * 8, (char*)xl + dst);
      GLDS(WTh + (size_t)(n0 + r) * 2048 + k0 + ss * 8, (char*)wh + dst);
      GLDS(WTl + (size_t)(n0 + r) * 2048 + k0 + ss * 8, (char*)wl + dst);
    }
    __syncthreads();
    #pragma unroll
    for (int ks = 0; ks < 2; ++ks) {
      const int kb = ks * 64 + (lane >> 4) * 16;
      short8 ah[4], al[4], bh[4], bl[4];
      #pragma unroll
      for (int mi = 0; mi < 4; ++mi) {
        int r = wm + mi * 16 + (lane & 15);
        ah[mi] = *(const short8*)((char*)xh + swz128(r, kb));
        al[mi] = *(const short8*)((char*)xl + swz128(r, kb));
      }
      #pragma unroll
      for (int ni = 0; ni < 4; ++ni) {
        int r = wn + ni * 16 + (lane & 15);
        bh[ni] = *(const short8*)((char*)wh + swz128(r, kb));
        bl[ni] = *(const short8*)((char*)wl + swz128(r, kb));
      }
      #pragma unroll
      for (int mi = 0; mi < 4; ++mi)
        #pragma unroll
        for (int ni = 0; ni < 4; ++ni) {
          acc[mi][ni] = MFMA(ah[mi], bh[ni], acc[mi][ni]);
          acc[mi][ni] = MFMA(al[mi], bh[ni], acc[mi][ni]);
          acc[mi][ni] = MFMA(ah[mi], bl[ni], acc[mi][ni]);
        }
    }
    __syncthreads();
  }
  #pragma unroll
  for (int mi = 0; mi < 4; ++mi)
    #pragma unroll
    for (int ni = 0; ni < 4; ++ni)
      #pragma unroll
      for (int rg = 0; rg < 4; ++rg) {
        int row = m0 + wm + mi * 16 + (lane >> 4) * 4 + rg;
        int col = n0 + wn + ni * 16 + (lane & 15);
        float y = acc[mi][ni][rg];
        unsigned short hi = f2bf(y);
        size_t o = (size_t)row * 2048 + col;
        Oh[o] = hi;
        Ol[o] = f2bf(y - bf2f(hi));
      }
}

// ---------------- K+V projection (merged, 256 blocks) ----------------
// blocks 0..3: K path (bf16x3, out k_h/k_l [4096][512]);
// blocks 4..7: V path (plain bf16, out VT[b][c][n]).
__global__ __launch_bounds__(256, 2) void kv_proj(
    const unsigned short* __restrict__ kxh, const unsigned short* __restrict__ kxl,
    const unsigned short* __restrict__ vxh,
    const unsigned short* __restrict__ wkh, const unsigned short* __restrict__ wkl,
    const unsigned short* __restrict__ wvh,
    unsigned short* __restrict__ koh, unsigned short* __restrict__ kol,
    unsigned short* __restrict__ vot) {
  __shared__ __align__(16) unsigned short xh[128 * 64];
  __shared__ __align__(16) unsigned short xl[128 * 64];
  __shared__ __align__(16) unsigned short wh[128 * 64];
  __shared__ __align__(16) unsigned short wl[128 * 64];
  const bool isK = blockIdx.x < 4;
  const int n0 = (isK ? blockIdx.x : blockIdx.x - 4) * 128;
  const int m0 = blockIdx.y * 128;
  const unsigned short* Ah = isK ? kxh : vxh;
  const unsigned short* Bh = isK ? wkh : wvh;
  const int t = threadIdx.x;
  const int wid = t >> 6, lane = t & 63;
  const int wm = (wid >> 1) * 64, wn = (wid & 1) * 64;
  f32x4 acc[4][4] = {};
  for (int k0 = 0; k0 < 2048; k0 += 64) {
    #pragma unroll
    for (int i = 0; i < 4; ++i) {
      int L = i * 4096 + t * 16;
      int r = L >> 7;
      int ss = ((L >> 4) & 7) ^ (r & 7);
      int dst = i * 4096 + wid * 1024;
      GLDS(Ah + (size_t)(m0 + r) * 2048 + k0 + ss * 8, (char*)xh + dst);
      GLDS(Bh + (size_t)(n0 + r) * 2048 + k0 + ss * 8, (char*)wh + dst);
      if (isK) {
        GLDS(kxl + (size_t)(m0 + r) * 2048 + k0 + ss * 8, (char*)xl + dst);
        GLDS(wkl + (size_t)(n0 + r) * 2048 + k0 + ss * 8, (char*)wl + dst);
      }
    }
    __syncthreads();
    #pragma unroll
    for (int ks = 0; ks < 2; ++ks) {
      const int kb = ks * 64 + (lane >> 4) * 16;
      short8 ah[4], al[4], bh[4], bl[4];
      #pragma unroll
      for (int mi = 0; mi < 4; ++mi) {
        int r = wm + mi * 16 + (lane & 15);
        ah[mi] = *(const short8*)((char*)xh + swz128(r, kb));
        if (isK) al[mi] = *(const short8*)((char*)xl + swz128(r, kb));
      }
      #pragma unroll
      for (int ni = 0; ni < 4; ++ni) {
        int r = wn + ni * 16 + (lane & 15);
        bh[ni] = *(const short8*)((char*)wh + swz128(r, kb));
        if (isK) bl[ni] = *(const short8*)((char*)wl + swz128(r, kb));
      }
      #pragma unroll
      for (int mi = 0; mi < 4; ++mi)
        #pragma unroll
        for (int ni = 0; ni < 4; ++ni) {
          acc[mi][ni] = MFMA(ah[mi], bh[ni], acc[mi][ni]);
          if (isK) {
            acc[mi][ni] = MFMA(al[mi], bh[ni], acc[mi][ni]);
            acc[mi][ni] = MFMA(ah[mi], bl[ni], acc[mi][ni]);
          }
        }
    }
    __syncthreads();
  }
  #pragma unroll
  for (int mi = 0; mi < 4; ++mi)
    #pragma unroll
    for (int ni = 0; ni < 4; ++ni)
      #pragma unroll
      for (int rg = 0; rg < 4; ++rg) {
        int row = m0 + wm + mi * 16 + (lane >> 4) * 4 + rg;
        int col = n0 + wn + ni * 16 + (lane & 15);
        float y = acc[mi][ni][rg];
        if (isK) {
          unsigned short hi = f2bf(y);
          size_t o = (size_t)row * 512 + col;
          koh[o] = hi;
          kol[o] = f2bf(y - bf2f(hi));
        } else {
          vot[((size_t)(row >> 11) * 512 + col) * 2048 + (row & 2047)] = f2bf(y);
        }
      }
}

// ---------------- fused attention ----------------
// One block: 128 q-rows of one (b,p). 4 waves x 32 rows. Q kept in regs
// (hi/lo). Pass A: row-sum l of exp(S). Pass B: recompute S, write
// w=exp(S)/l (fp32), P->LDS, PV MFMA (plain bf16).
__global__ __launch_bounds__(256, 2) void attn_kernel(
    const unsigned short* __restrict__ Qh, const unsigned short* __restrict__ Ql,
    const unsigned short* __restrict__ Kh, const unsigned short* __restrict__ Kl,
    const unsigned short* __restrict__ VT,
    float* __restrict__ Wout,
    unsigned short* __restrict__ Ctx) {
  __shared__ __align__(16) char lds[65536];
  const int bp = blockIdx.y;
  const int b = bp >> 4, p = bp & 15;
  const int hq = (p & 3) * 4 + (p >> 2);
  const int kv = p & 3;
  const int n0 = blockIdx.x * 128;
  const int t = threadIdx.x, wid = t >> 6, lane = t & 63;
  const int wrow = wid * 32;

  {
    size_t qbase = ((size_t)(b * 2048 + n0)) * 2048 + hq * 128;
    #pragma unroll
    for (int i = 0; i < 8; ++i) {
      int L = i * 4096 + t * 16;
      int r = L >> 8;
      int ss = ((L >> 4) & 15) ^ (r & 15);
      GLDS(Qh + qbase + (size_t)r * 2048 + ss * 8, lds + i * 4096 + wid * 1024);
      GLDS(Ql + qbase + (size_t)r * 2048 + ss * 8, lds + 32768 + i * 4096 + wid * 1024);
    }
  }
  __syncthreads();
  short8 qa_h[2][4], qa_l[2][4];
  #pragma unroll
  for (int mf = 0; mf < 2; ++mf)
    #pragma unroll
    for (int ks = 0; ks < 4; ++ks) {
      int r = wrow + mf * 16 + (lane & 15);
      int byte = ks * 64 + (lane >> 4) * 16;
      qa_h[mf][ks] = *(const short8*)(lds + swz256(r, byte));
      qa_l[mf][ks] = *(const short8*)(lds + 32768 + swz256(r, byte));
    }
  __syncthreads();

  const size_t kbase = (size_t)b * 2048 * 512 + kv * 128;
  float lp[2][4];
  #pragma unroll
  for (int mf = 0; mf < 2; ++mf)
    #pragma unroll
    for (int rg = 0; rg < 4; ++rg) lp[mf][rg] = 0.f;

  // ---- pass A: row-sum of exp(S) ----
  for (int s0 = 0; s0 < 2048; s0 += 64) {
    #pragma unroll
    for (int i = 0; i < 4; ++i) {
      int L = i * 4096 + t * 16;
      int r = L >> 8;
      int ss = ((L >> 4) & 15) ^ (r & 15);
      GLDS(Kh + kbase + (size_t)(s0 + r) * 512 + ss * 8, lds + i * 4096 + wid * 1024);
      GLDS(Kl + kbase + (size_t)(s0 + r) * 512 + ss * 8, lds + 16384 + i * 4096 + wid * 1024);
    }
    __syncthreads();
    f32x4 sc[2][4] = {};
    #pragma unroll
    for (int sf = 0; sf < 4; ++sf)
      #pragma unroll
      for (int ks = 0; ks < 4; ++ks) {
        int r = sf * 16 + (lane & 15);
        int byte = ks * 64 + (lane >> 4) * 16;
        short8 bh = *(const short8*)(lds + swz256(r, byte));
        short8 bl = *(const short8*)(lds + 16384 + swz256(r, byte));
        #pragma unroll
        for (int mf = 0; mf < 2; ++mf) {
          sc[mf][sf] = MFMA(qa_h[mf][ks], bh, sc[mf][sf]);
          sc[mf][sf] = MFMA(qa_l[mf][ks], bh, sc[mf][sf]);
          sc[mf][sf] = MFMA(qa_h[mf][ks], bl, sc[mf][sf]);
        }
      }
    #pragma unroll
    for (int mf = 0; mf < 2; ++mf)
      #pragma unroll
      for (int rg = 0; rg < 4; ++rg)
        lp[mf][rg] += __expf(sc[mf][0][rg]) + __expf(sc[mf][1][rg]) +
                      __expf(sc[mf][2][rg]) + __expf(sc[mf][3][rg]);
    __syncthreads();
  }

  float invl[2][4];
  #pragma unroll
  for (int mf = 0; mf < 2; ++mf)
    #pragma unroll
    for (int rg = 0; rg < 4; ++rg) {
      float sm = lp[mf][rg];
      sm += __shfl_xor(sm, 1);
      sm += __shfl_xor(sm, 2);
      sm += __shfl_xor(sm, 4);
      sm += __shfl_xor(sm, 8);
      invl[mf][rg] = 1.0f / sm;
    }

  // ---- pass B: recompute S, write weights, PV ----
  f32x4 cacc[2][8] = {};
  const size_t vbase = ((size_t)b * 512 + kv * 128) * 2048;
  const size_t wbase = ((size_t)bp * 2048 + n0) * 2048;
  for (int s0 = 0; s0 < 2048; s0 += 64) {
    #pragma unroll
    for (int i = 0; i < 4; ++i) {
      int L = i * 4096 + t * 16;
      int r = L >> 8;
      int ss = ((L >> 4) & 15) ^ (r & 15);
      GLDS(Kh + kbase + (size_t)(s0 + r) * 512 + ss * 8, lds + i * 4096 + wid * 1024);
      GLDS(Kl + kbase + (size_t)(s0 + r) * 512 + ss * 8, lds + 16384 + i * 4096 + wid * 1024);
    }
    #pragma unroll
    for (int i = 0; i < 4; ++i) {
      int L = i * 4096 + t * 16;
      int r = L >> 7;
      int ss = ((L >> 4) & 7) ^ (r & 7);
      GLDS(VT + vbase + (size_t)r * 2048 + s0 + ss * 8, lds + 32768 + i * 4096 + wid * 1024);
    }
    __syncthreads();
    f32x4 sc[2][4] = {};
    #pragma unroll
    for (int sf = 0; sf < 4; ++sf)
      #pragma unroll
      for (int ks = 0; ks < 4; ++ks) {
        int r = sf * 16 + (lane & 15);
        int byte = ks * 64 + (lane >> 4) * 16;
        short8 bh = *(const short8*)(lds + swz256(r, byte));
        short8 bl = *(const short8*)(lds + 16384 + swz256(r, byte));
        #pragma unroll
        for (int mf = 0; mf < 2; ++mf) {
          sc[mf][sf] = MFMA(qa_h[mf][ks], bh, sc[mf][sf]);
          sc[mf][sf] = MFMA(qa_l[mf][ks], bh, sc[mf][sf]);
          sc[mf][sf] = MFMA(qa_h[mf][ks], bl, sc[mf][sf]);
        }
      }
    #pragma unroll
    for (int mf = 0; mf < 2; ++mf)
      #pragma unroll
      for (int sf = 0; sf < 4; ++sf)
        #pragma unroll
        for (int rg = 0; rg < 4; ++rg) {
          float w = __expf(sc[mf][sf][rg]) * invl[mf][rg];
          int lr = mf * 16 + (lane >> 4) * 4 + rg;
          int col = sf * 16 + (lane & 15);
          Wout[wbase + (size_t)(wrow + lr) * 2048 + s0 + col] = w;
          *(unsigned short*)(lds + 49152 + wid * 4096 + swz128(lr, col * 2)) = f2bf(w);
        }
    #pragma unroll
    for (int ks = 0; ks < 2; ++ks) {
      short8 pa[2];
      #pragma unroll
      for (int mf = 0; mf < 2; ++mf)
        pa[mf] = *(const short8*)(lds + 49152 + wid * 4096 +
                                  swz128(mf * 16 + (lane & 15), ks * 64 + (lane >> 4) * 16));
      #pragma unroll
      for (int df = 0; df < 8; ++df) {
        short8 vb = *(const short8*)(lds + 32768 +
                                     swz128(df * 16 + (lane & 15), ks * 64 + (lane >> 4) * 16));
        #pragma unroll
        for (int mf = 0; mf < 2; ++mf)
          cacc[mf][df] = MFMA(pa[mf], vb, cacc[mf][df]);
      }
    }
    __syncthreads();
  }
  #pragma unroll
  for (int mf = 0; mf < 2; ++mf)
    #pragma unroll
    for (int df = 0; df < 8; ++df)
      #pragma unroll
      for (int rg = 0; rg < 4; ++rg) {
        int grow = b * 2048 + n0 + wrow + mf * 16 + (lane >> 4) * 4 + rg;
        int col = p * 128 + df * 16 + (lane & 15);
        Ctx[(size_t)grow * 2048 + col] = f2bf(cacc[mf][df][rg]);
      }
}

// ---------------- output projection (plain bf16) ----------------
__global__ __launch_bounds__(256, 2) void gemm_out(
    const unsigned short* __restrict__ A,   // ctx bf16 [4096][2048]
    const unsigned short* __restrict__ BT,  // WoT bf16 [2048][2048]
    float* __restrict__ Cout) {             // [4096][2048]
  __shared__ __align__(16) unsigned short ash[128 * 64];
  __shared__ __align__(16) unsigned short bsh[128 * 64];
  const int t = threadIdx.x;
  const int n0 = blockIdx.x * 128, m0 = blockIdx.y * 128;
  const int wid = t >> 6, lane = t & 63;
  const int wm = (wid >> 1) * 64, wn = (wid & 1) * 64;
  f32x4 acc[4][4] = {};
  for (int k0 = 0; k0 < 2048; k0 += 64) {
    #pragma unroll
    for (int i = 0; i < 4; ++i) {
      int L = i * 4096 + t * 16;
      int r = L >> 7;
      int ss = ((L >> 4) & 7) ^ (r & 7);
      GLDS(A + (size_t)(m0 + r) * 2048 + k0 + ss * 8, (char*)ash + i * 4096 + wid * 1024);
      GLDS(BT + (size_t)(n0 + r) * 2048 + k0 + ss * 8, (char*)bsh + i * 4096 + wid * 1024);
    }
    __syncthreads();
    #pragma unroll
    for (int ks = 0; ks < 2; ++ks) {
      const int kb = ks * 64 + (lane >> 4) * 16;
      short8 af[4], bfr[4];
      #pragma unroll
      for (int mi = 0; mi < 4; ++mi)
        af[mi] = *(const short8*)((char*)ash + swz128(wm + mi * 16 + (lane & 15), kb));
      #pragma unroll
      for (int ni = 0; ni < 4; ++ni)
        bfr[ni] = *(const short8*)((char*)bsh + swz128(wn + ni * 16 + (lane & 15), kb));
      #pragma unroll
      for (int mi = 0; mi < 4; ++mi)
        #pragma unroll
        for (int ni = 0; ni < 4; ++ni)
          acc[mi][ni] = MFMA(af[mi], bfr[ni], acc[mi][ni]);
    }
    __syncthreads();
  }
  #pragma unroll
  for (int mi = 0; mi < 4; ++mi)
    #pragma unroll
    for (int ni = 0; ni < 4; ++ni)
      #pragma unroll
      for (int rg = 0; rg < 4; ++rg) {
        int row = m0 + wm + mi * 16 + (lane >> 4) * 4 + rg;
        int col = n0 + wn + ni * 16 + (lane & 15);
        Cout[(size_t)row * 2048 + col] = acc[mi][ni][rg];
      }
}

extern "C" void kernel_launch(void* const* d_in, const int* in_sizes, int n_in,
                              void* d_out, int out_size, void* d_ws, size_t ws_size,
                              hipStream_t stream) {
  const float* query = (const float*)d_in[0];
  const float* key   = (const float*)d_in[1];
  const float* value = (const float*)d_in[2];
  const float* Wq = (const float*)d_in[3];
  const float* Wk = (const float*)d_in[4];
  const float* Wv = (const float*)d_in[5];
  const float* Wo = (const float*)d_in[6];
  float* out = (float*)d_out;            // attn_output: 2*2048*2048 fp32
  float* wts = out + 8388608;            // weights: 32*2048*2048 fp32

  char* ws = (char*)d_ws;
  unsigned short* wqT_h = (unsigned short*)(ws);              // 8 MB
  unsigned short* wqT_l = (unsigned short*)(ws + 8388608);    // 8 MB
  unsigned short* wkT_h = (unsigned short*)(ws + 16777216);   // 2 MB
  unsigned short* wkT_l = (unsigned short*)(ws + 18874368);   // 2 MB
  unsigned short* wvT_h = (unsigned short*)(ws + 20971520);   // 2 MB
  unsigned short* q_h   = (unsigned short*)(ws + 23068672);   // 16 MB
  unsigned short* q_l   = (unsigned short*)(ws + 39845888);   // 16 MB
  unsigned short* k_h   = (unsigned short*)(ws + 56623104);   // 4 MB
  unsigned short* k_l   = (unsigned short*)(ws + 60817408);   // 4 MB
  unsigned short* vT    = (unsigned short*)(ws + 65011712);   // 4 MB
  unsigned short* qx_h  = (unsigned short*)(ws + 69206016);   // 16 MB
  unsigned short* qx_l  = (unsigned short*)(ws + 85983232);   // 16 MB
  unsigned short* kx_h  = (unsigned short*)(ws + 102760448);  // 16 MB
  unsigned short* kx_l  = (unsigned short*)(ws + 119537664);  // 16 MB
  unsigned short* vx_h  = (unsigned short*)(ws + 136314880);  // 16 MB (tot 152 MB)
  unsigned short* ctxb  = (unsigned short*)(ws);              // alias wqT_h/l (dead by attn)
  unsigned short* woT   = (unsigned short*)(ws + 23068672);   // alias q_h (dead by O-proj)

  convert_split3<<<dim3(24576), dim3(256), 0, stream>>>(query, key, value,
                                                        qx_h, qx_l, kx_h, kx_l, vx_h);
  transpose_split<<<dim3(64, 64), dim3(32, 32), 0, stream>>>(Wq, wqT_h, wqT_l, 2048, 2048);
  transpose_split<<<dim3(16, 64), dim3(32, 32), 0, stream>>>(Wk, wkT_h, wkT_l, 2048, 512);
  transpose_split<<<dim3(16, 64), dim3(32, 32), 0, stream>>>(Wv, wvT_h, (unsigned short*)nullptr, 2048, 512);
  qproj_kernel<<<dim3(16, 32), dim3(256), 0, stream>>>(qx_h, qx_l, wqT_h, wqT_l, q_h, q_l);
  kv_proj<<<dim3(8, 32), dim3(256), 0, stream>>>(kx_h, kx_l, vx_h, wkT_h, wkT_l, wvT_h,
                                                 k_h, k_l, vT);
  attn_kernel<<<dim3(16, 32), dim3(256), 0, stream>>>(q_h, q_l, k_h, k_l, vT, wts, ctxb);
  transpose_split<<<dim3(64, 64), dim3(32, 32), 0, stream>>>(Wo, woT, (unsigned short*)nullptr, 2048, 2048);
  gemm_out<<<dim3(16, 32), dim3(256), 0, stream>>>(ctxb, woT, out);
}